// Round 2
// baseline (1121.246 us; speedup 1.0000x reference)
//
#include <hip/hip_runtime.h>

// Problem constants
#define BB 16
#define SS 1024
#define DD 768

typedef __bf16 bf16x4 __attribute__((ext_vector_type(4)));
typedef __bf16 bf16x8 __attribute__((ext_vector_type(8)));
typedef float f32x4 __attribute__((ext_vector_type(4)));

// Split fp32 -> hi/lo bf16 (x ~= hi + lo, error ~2^-17 rel)
__device__ __forceinline__ void store_split(__bf16* hi, __bf16* lo, int off, float4 v) {
  bf16x4 h, lw;
  h[0] = (__bf16)v.x; lw[0] = (__bf16)(v.x - (float)h[0]);
  h[1] = (__bf16)v.y; lw[1] = (__bf16)(v.y - (float)h[1]);
  h[2] = (__bf16)v.z; lw[2] = (__bf16)(v.z - (float)h[2]);
  h[3] = (__bf16)v.w; lw[3] = (__bf16)(v.w - (float)h[3]);
  *(bf16x4*)(hi + off) = h;
  *(bf16x4*)(lo + off) = lw;
}

// ---------------------------------------------------------------------------
// NT GEMM, fp32 in / fp32 out, split-bf16 MFMA (3 MFMAs: hh + hl + lh).
// C[z][m][n] = sum_k A[z][m][k] * Bt[z][n][k] (+ bias[n])
// 128x128 tile, BK=32, 256 threads. M,N % 128 == 0, K % 32 == 0.
// CT=1: write C transposed per 1024-row batch: C[(b*N+c)*1024 + s], b=r>>10.
// ---------------------------------------------------------------------------
template<int CT, int BIAS>
__global__ __launch_bounds__(256) void gemm_nt_f32(
    const float* __restrict__ A, long long aB,
    const float* __restrict__ Bt, long long bB,
    const float* __restrict__ bias,
    float* __restrict__ C, long long cB,
    int M, int N, int K)
{
  __shared__ __attribute__((aligned(16))) __bf16 lAhi[128 * 32];
  __shared__ __attribute__((aligned(16))) __bf16 lAlo[128 * 32];
  __shared__ __attribute__((aligned(16))) __bf16 lBhi[128 * 32];
  __shared__ __attribute__((aligned(16))) __bf16 lBlo[128 * 32];

  const int t = threadIdx.x;
  const int z = blockIdx.z;
  const float* Ab = A + (size_t)z * aB;
  const float* Bb = Bt + (size_t)z * bB;
  const int m0 = blockIdx.x * 128, n0 = blockIdx.y * 128;
  const int l = t & 63, w = t >> 6;
  const int wr = (w >> 1) * 64, wc = (w & 1) * 64;
  const int lrow = l & 15, lkb = (l >> 4) * 8;
  const int fv = t & 7, r8 = t >> 3;   // staging: float4 idx in row, row

  f32x4 acc[4][4] = {};

  for (int k0 = 0; k0 < K; k0 += 32) {
    const float* Ap = Ab + (size_t)(m0 + r8) * K + k0 + fv * 4;
    const float* Bp = Bb + (size_t)(n0 + r8) * K + k0 + fv * 4;
    float4 va0 = *(const float4*)(Ap);
    float4 va1 = *(const float4*)(Ap + (size_t)32 * K);
    float4 va2 = *(const float4*)(Ap + (size_t)64 * K);
    float4 va3 = *(const float4*)(Ap + (size_t)96 * K);
    float4 vb0 = *(const float4*)(Bp);
    float4 vb1 = *(const float4*)(Bp + (size_t)32 * K);
    float4 vb2 = *(const float4*)(Bp + (size_t)64 * K);
    float4 vb3 = *(const float4*)(Bp + (size_t)96 * K);

    const int o0 = r8 * 32 + fv * 4;
    store_split(lAhi, lAlo, o0,            va0);
    store_split(lAhi, lAlo, o0 + 32 * 32,  va1);
    store_split(lAhi, lAlo, o0 + 64 * 32,  va2);
    store_split(lAhi, lAlo, o0 + 96 * 32,  va3);
    store_split(lBhi, lBlo, o0,            vb0);
    store_split(lBhi, lBlo, o0 + 32 * 32,  vb1);
    store_split(lBhi, lBlo, o0 + 64 * 32,  vb2);
    store_split(lBhi, lBlo, o0 + 96 * 32,  vb3);
    __syncthreads();

    bf16x8 ah[4], al[4], bh[4], bl[4];
    #pragma unroll
    for (int m = 0; m < 4; m++) {
      const int o = (wr + m * 16 + lrow) * 32 + lkb;
      ah[m] = *(const bf16x8*)&lAhi[o];
      al[m] = *(const bf16x8*)&lAlo[o];
    }
    #pragma unroll
    for (int n = 0; n < 4; n++) {
      const int o = (wc + n * 16 + lrow) * 32 + lkb;
      bh[n] = *(const bf16x8*)&lBhi[o];
      bl[n] = *(const bf16x8*)&lBlo[o];
    }
    #pragma unroll
    for (int m = 0; m < 4; m++)
      #pragma unroll
      for (int n = 0; n < 4; n++)
        acc[m][n] = __builtin_amdgcn_mfma_f32_16x16x32_bf16(ah[m], bh[n], acc[m][n], 0, 0, 0);
    #pragma unroll
    for (int m = 0; m < 4; m++)
      #pragma unroll
      for (int n = 0; n < 4; n++)
        acc[m][n] = __builtin_amdgcn_mfma_f32_16x16x32_bf16(ah[m], bl[n], acc[m][n], 0, 0, 0);
    #pragma unroll
    for (int m = 0; m < 4; m++)
      #pragma unroll
      for (int n = 0; n < 4; n++)
        acc[m][n] = __builtin_amdgcn_mfma_f32_16x16x32_bf16(al[m], bh[n], acc[m][n], 0, 0, 0);
    __syncthreads();
  }

  // Epilogue: C/D layout col = lane&15, row = 4*(lane>>4) + j
  const int crow = (l >> 4) * 4, ccol = l & 15;
  #pragma unroll
  for (int m = 0; m < 4; m++) {
    const int rq = m0 + wr + m * 16 + crow;
    #pragma unroll
    for (int n = 0; n < 4; n++) {
      const int c = n0 + wc + n * 16 + ccol;
      const float bv = BIAS ? bias[c] : 0.0f;
      if (CT) {
        float4 o;
        o.x = acc[m][n][0] + bv;
        o.y = acc[m][n][1] + bv;
        o.z = acc[m][n][2] + bv;
        o.w = acc[m][n][3] + bv;
        const int b = rq >> 10, s = rq & 1023;
        *(float4*)&C[((size_t)(b * N + c) << 10) + s] = o;
      } else {
        #pragma unroll
        for (int j = 0; j < 4; j++)
          C[(size_t)z * cB + (size_t)(rq + j) * N + c] = acc[m][n][j] + bv;
      }
    }
  }
}

// fp32 [R][C] -> fp32 [C][R] (weights)
__global__ __launch_bounds__(256) void transpose_f2f(const float* __restrict__ in,
                                                     float* __restrict__ outp, int R, int C)
{
  __shared__ float tile[32][33];
  const int r0 = blockIdx.y * 32, c0 = blockIdx.x * 32;
  const int tx = threadIdx.x & 31, ty = threadIdx.x >> 5;  // 32 x 8
  #pragma unroll
  for (int i = 0; i < 4; i++)
    tile[ty + i * 8][tx] = in[(size_t)(r0 + ty + i * 8) * C + c0 + tx];
  __syncthreads();
  #pragma unroll
  for (int i = 0; i < 4; i++)
    outp[(size_t)(c0 + ty + i * 8) * R + r0 + tx] = tile[tx][ty + i * 8];
}

// fp32 [R][C] -> [C][R], batched over blockIdx.z
__global__ __launch_bounds__(256) void transpose_b2b_f32(const float* __restrict__ in, long long inB,
                                                         float* __restrict__ outp, long long outB,
                                                         int R, int C)
{
  __shared__ float tile[32][33];
  const float* ib = in + (size_t)blockIdx.z * inB;
  float* ob = outp + (size_t)blockIdx.z * outB;
  const int r0 = blockIdx.y * 32, c0 = blockIdx.x * 32;
  const int tx = threadIdx.x & 31, ty = threadIdx.x >> 5;
  #pragma unroll
  for (int i = 0; i < 4; i++)
    tile[ty + i * 8][tx] = ib[(size_t)(r0 + ty + i * 8) * C + c0 + tx];
  __syncthreads();
  #pragma unroll
  for (int i = 0; i < 4; i++)
    ob[(size_t)(c0 + ty + i * 8) * R + r0 + tx] = tile[tx][ty + i * 8];
}

// ---------------------------------------------------------------------------
// In-place row softmax: X = softmax(X * scale) rowwise, fp32. L = VPT*256.
// One block per row; all reads precede all writes within the block.
// ---------------------------------------------------------------------------
template<int VPT>
__global__ __launch_bounds__(256) void softmax_rows_f32(float* __restrict__ X,
                                                        int L, float scale)
{
  const size_t base = (size_t)blockIdx.x * L;
  const int t = threadIdx.x;
  float v[VPT];
  float m = -3.4e38f;
  #pragma unroll
  for (int j = 0; j < VPT; j++) { v[j] = X[base + t + j * 256]; m = fmaxf(m, v[j]); }
  __shared__ float red[256];
  red[t] = m; __syncthreads();
  #pragma unroll
  for (int off = 128; off > 0; off >>= 1) {
    if (t < off) red[t] = fmaxf(red[t], red[t + off]);
    __syncthreads();
  }
  m = red[0]; __syncthreads();
  float s = 0.0f;
  #pragma unroll
  for (int j = 0; j < VPT; j++) { v[j] = __expf((v[j] - m) * scale); s += v[j]; }
  red[t] = s; __syncthreads();
  #pragma unroll
  for (int off = 128; off > 0; off >>= 1) {
    if (t < off) red[t] += red[t + off];
    __syncthreads();
  }
  const float inv = 1.0f / red[0];
  #pragma unroll
  for (int j = 0; j < VPT; j++) X[base + t + j * 256] = v[j] * inv;
}

// ---------------------------------------------------------------------------
// LayerNorm over (S,D) jointly per batch, fp32, in-place apply
// ---------------------------------------------------------------------------
__global__ __launch_bounds__(256) void ln_partial(const float* __restrict__ src,
                                                  float* __restrict__ part)
{
  const int b = blockIdx.y, ch = blockIdx.x;   // 64 chunks per batch
  const float4* p = (const float4*)(src + (size_t)b * SS * DD) + (size_t)ch * 3072;
  const int t = threadIdx.x;
  float s = 0.0f, q = 0.0f;
  #pragma unroll
  for (int i = 0; i < 12; i++) {
    float4 v = p[t + i * 256];
    s += v.x + v.y + v.z + v.w;
    q += v.x * v.x + v.y * v.y + v.z * v.z + v.w * v.w;
  }
  __shared__ float rs[256], rq[256];
  rs[t] = s; rq[t] = q; __syncthreads();
  #pragma unroll
  for (int off = 128; off > 0; off >>= 1) {
    if (t < off) { rs[t] += rs[t + off]; rq[t] += rq[t + off]; }
    __syncthreads();
  }
  if (t == 0) { part[(b * 64 + ch) * 2] = rs[0]; part[(b * 64 + ch) * 2 + 1] = rq[0]; }
}

__global__ void ln_final(const float* __restrict__ part, float* __restrict__ stats)
{
  const int b = blockIdx.x, t = threadIdx.x;  // 64 threads = 1 wave
  float s = part[(b * 64 + t) * 2];
  float q = part[(b * 64 + t) * 2 + 1];
  #pragma unroll
  for (int off = 32; off > 0; off >>= 1) { s += __shfl_down(s, off); q += __shfl_down(q, off); }
  if (t == 0) {
    const float invN = 1.0f / (float)(SS * DD);
    float mu = s * invN;
    float var = q * invN - mu * mu;
    stats[b * 2] = mu;
    stats[b * 2 + 1] = rsqrtf(var + 1e-8f);
  }
}

__global__ __launch_bounds__(256) void ln_apply(float* __restrict__ data,
                                                const float* __restrict__ g,
                                                const float* __restrict__ bta,
                                                const float* __restrict__ stats)
{
  const long long n4 = (long long)BB * SS * DD / 4;
  const int SD4 = SS * DD / 4;
  for (long long i = (long long)blockIdx.x * 256 + threadIdx.x; i < n4;
       i += (long long)gridDim.x * 256) {
    const int b = (int)(i / SD4);
    const int sd4 = (int)(i - (long long)b * SD4);
    const float mu = stats[b * 2], rs = stats[b * 2 + 1];
    float4 v = ((const float4*)data)[i];
    float4 gg = ((const float4*)g)[sd4];
    float4 bb = ((const float4*)bta)[sd4];
    float4 o;
    o.x = (v.x - mu) * rs * gg.x + bb.x;
    o.y = (v.y - mu) * rs * gg.y + bb.y;
    o.z = (v.z - mu) * rs * gg.z + bb.z;
    o.w = (v.w - mu) * rs * gg.w + bb.w;
    ((float4*)data)[i] = o;
  }
}

// gate[b,s] = dot(out_N[b,s,:], W_sgsa) + b_sgsa ; one wave per row
__global__ __launch_bounds__(256) void gate_k(const float* __restrict__ outN,
                                              const float* __restrict__ wsg,
                                              const float* __restrict__ bsg,
                                              float* __restrict__ gate)
{
  const int row = blockIdx.x * 4 + (threadIdx.x >> 6);
  const int l = threadIdx.x & 63;
  const float* src = outN + (size_t)row * DD;
  float s = 0.0f;
  #pragma unroll
  for (int i = 0; i < 12; i++) s += src[l + i * 64] * wsg[l + i * 64];
  #pragma unroll
  for (int off = 32; off > 0; off >>= 1) s += __shfl_down(s, off);
  if (l == 0) gate[row] = s + bsg[0];
}

// Per (b,d): mean/max over s of tokens and gate*out_N -> pooled [B][4D]
__global__ __launch_bounds__(256) void pool_k(const float* __restrict__ tokens,
                                              const float* __restrict__ outN,
                                              const float* __restrict__ gate,
                                              float* __restrict__ pooled)
{
  const int idx = blockIdx.x * 256 + threadIdx.x;  // < B*D
  const int b = idx / DD, d = idx - b * DD;
  const float* tb = tokens + (size_t)b * SS * DD + d;
  const float* ob = outN + (size_t)b * SS * DD + d;
  const float* gb = gate + (size_t)b * SS;
  float mt = 0.0f, mo = 0.0f, xt = -3.4e38f, xo = -3.4e38f;
  for (int s = 0; s < SS; s++) {
    const float tv = tb[(size_t)s * DD];
    const float ov = ob[(size_t)s * DD] * gb[s];
    mt += tv; mo += ov;
    xt = fmaxf(xt, tv); xo = fmaxf(xo, ov);
  }
  const float inv = 1.0f / (float)SS;
  pooled[(size_t)b * 3072 + d]        = mt * inv;
  pooled[(size_t)b * 3072 + 768 + d]  = mo * inv;
  pooled[(size_t)b * 3072 + 1536 + d] = xt;
  pooled[(size_t)b * 3072 + 2304 + d] = xo;
}

__global__ __launch_bounds__(256) void fc_k(const float* __restrict__ pooled,
                                            const float* __restrict__ Wf,
                                            const float* __restrict__ bf,
                                            float* __restrict__ outp)
{
  const int b = blockIdx.x, t = threadIdx.x;
  float p0 = 0.0f, p1 = 0.0f;
  #pragma unroll
  for (int i = 0; i < 12; i++) {
    const int j = t + i * 256;
    const float pv = pooled[(size_t)b * 3072 + j];
    p0 += pv * Wf[j * 2];
    p1 += pv * Wf[j * 2 + 1];
  }
  __shared__ float r0[256], r1[256];
  r0[t] = p0; r1[t] = p1; __syncthreads();
  #pragma unroll
  for (int off = 128; off > 0; off >>= 1) {
    if (t < off) { r0[t] += r0[t + off]; r1[t] += r1[t + off]; }
    __syncthreads();
  }
  if (t == 0) {
    outp[b * 2 + 0] = r0[0] + bf[0];
    outp[b * 2 + 1] = r1[0] + bf[1];
  }
}

// ---------------------------------------------------------------------------
// Host orchestration. All intermediates fp32. Workspace peak ~225.5 MB.
// Region map (byte offsets):
//   X3z0 @ 0         (50.33MB): K -> OUT -> out_ln(in-place) -> attN_sc/attN(in-place)
//   X3z1 @ 50331648  (50.33MB): Q -> QtN -> out_N
//   X3z2 @ 100663296 (50.33MB): Vt -> V_N
//   X0   @ 150994944 (67.11MB): scores/att(in-place) -> KtN -> attNT
//   Wt   @ 218103808 (7.08MB), small tail after.
// ---------------------------------------------------------------------------
extern "C" void kernel_launch(void* const* d_in, const int* in_sizes, int n_in,
                              void* d_out, int out_size, void* d_ws, size_t ws_size,
                              hipStream_t stream)
{
  const float* tokens = (const float*)d_in[0];
  const float* Wk  = (const float*)d_in[1];
  const float* bk  = (const float*)d_in[2];
  const float* Wq  = (const float*)d_in[3];
  const float* bq  = (const float*)d_in[4];
  const float* Wv  = (const float*)d_in[5];
  const float* bv  = (const float*)d_in[6];
  const float* lng = (const float*)d_in[7];
  const float* lnb = (const float*)d_in[8];
  const float* Wsg = (const float*)d_in[9];
  const float* bsg = (const float*)d_in[10];
  const float* Wf  = (const float*)d_in[11];
  const float* bfn = (const float*)d_in[12];
  float* outp = (float*)d_out;
  (void)in_sizes; (void)n_in; (void)out_size; (void)ws_size;

  char* ws = (char*)d_ws;
  float* X3z0 = (float*)(ws + 0);            // 50331648 B
  float* X3z1 = (float*)(ws + 50331648);     // 50331648 B
  float* X3z2 = (float*)(ws + 100663296);    // 50331648 B
  float* X0   = (float*)(ws + 150994944);    // 67108864 B
  float* Wt   = (float*)(ws + 218103808);    // 7077888 B ([3][768*768])
  float* part   = (float*)(ws + 225181696);  // 8192 B
  float* stats  = (float*)(ws + 225189888);  // 128 B
  float* gate   = (float*)(ws + 225190016);  // 65536 B
  float* pooled = (float*)(ws + 225255552);  // 196608 B  (end ~225.45MB)

  const float fact = 0.036084391824351615f;  // 1/sqrt(768)
  const long long SD = (long long)SS * DD;   // 786432
  const long long S2 = (long long)SS * SS;   // 1048576
  const long long D2 = (long long)DD * DD;   // 589824

  // 1. Weights -> W^T fp32
  transpose_f2f<<<dim3(24, 24), 256, 0, stream>>>(Wk, Wt,               768, 768);
  transpose_f2f<<<dim3(24, 24), 256, 0, stream>>>(Wq, Wt + 589824,      768, 768);
  transpose_f2f<<<dim3(24, 24), 256, 0, stream>>>(Wv, Wt + 2 * 589824,  768, 768);

  // 2. Stage-1 projections (M=16384, N=768, K=768)
  gemm_nt_f32<0, 1><<<dim3(128, 6, 1), 256, 0, stream>>>(tokens, 0, Wt, 0, bk,
                                                         X3z0, 0, BB * SS, DD, DD);
  gemm_nt_f32<0, 1><<<dim3(128, 6, 1), 256, 0, stream>>>(tokens, 0, Wt + 589824, 0, bq,
                                                         X3z1, 0, BB * SS, DD, DD);
  // V written transposed per batch: Vt [16][768][1024]
  gemm_nt_f32<1, 1><<<dim3(128, 6, 1), 256, 0, stream>>>(tokens, 0, Wt + 2 * 589824, 0, bv,
                                                         X3z2, 0, BB * SS, DD, DD);

  // 3. scores[b,s,t] = Q.K^T -> X0 [16][1024][1024]
  gemm_nt_f32<0, 0><<<dim3(8, 8, 16), 256, 0, stream>>>(X3z1, SD, X3z0, SD, nullptr,
                                                        X0, S2, SS, SS, DD);
  // 4. att = softmax in-place
  softmax_rows_f32<4><<<BB * SS, 256, 0, stream>>>(X0, SS, fact);
  // 5. OUT[b,s,d] = att @ V -> X3z0 (K dead)
  gemm_nt_f32<0, 0><<<dim3(8, 6, 16), 256, 0, stream>>>(X0, S2, X3z2, SD, nullptr,
                                                        X3z0, SD, SS, DD, SS);
  // 6. LayerNorm over (S,D) per batch, in-place on X3z0
  ln_partial<<<dim3(64, 16), 256, 0, stream>>>(X3z0, part);
  ln_final<<<16, 64, 0, stream>>>(part, stats);
  ln_apply<<<2048, 256, 0, stream>>>(X3z0, lng, lnb, stats);

  // 7. Stage-2 projections from out_ln (X3z0); K_N,Q_N written transposed
  gemm_nt_f32<1, 1><<<dim3(128, 6, 1), 256, 0, stream>>>(X3z0, 0, Wt, 0, bk,
                                                         X0, 0, BB * SS, DD, DD);    // KtN [16][768][1024]
  gemm_nt_f32<1, 1><<<dim3(128, 6, 1), 256, 0, stream>>>(X3z0, 0, Wt + 589824, 0, bq,
                                                         X3z1, 0, BB * SS, DD, DD);  // QtN [16][768][1024]
  gemm_nt_f32<0, 1><<<dim3(128, 6, 1), 256, 0, stream>>>(X3z0, 0, Wt + 2 * 589824, 0, bv,
                                                         X3z2, 0, BB * SS, DD, DD);  // V_N [16384][768]

  // 8. attN_sc[b,d,e] = sum_s Q_N[s,d] K_N[s,e] = QtN .NT. KtN -> X3z0 (out_ln dead)
  gemm_nt_f32<0, 0><<<dim3(6, 6, 16), 256, 0, stream>>>(X3z1, SD, X0, SD, nullptr,
                                                        X3z0, D2, DD, DD, SS);
  // 9. attN = softmax in-place on X3z0 [16][768][768]
  softmax_rows_f32<3><<<BB * DD, 256, 0, stream>>>(X3z0, DD, fact);
  // 10. attNT = attN^T per batch -> X0 (KtN dead)
  transpose_b2b_f32<<<dim3(24, 24, 16), 256, 0, stream>>>(X3z0, D2, X0, D2, DD, DD);
  // 11. out_N[b,s,e] = V_N .NT. attNT -> X3z1 (QtN dead)
  gemm_nt_f32<0, 0><<<dim3(8, 6, 16), 256, 0, stream>>>(X3z2, SD, X0, D2, nullptr,
                                                        X3z1, SD, SS, DD, DD);

  // 12. gate, pooling, FC
  gate_k<<<4096, 256, 0, stream>>>(X3z1, Wsg, bsg, gate);
  pool_k<<<48, 256, 0, stream>>>(tokens, X3z1, gate, pooled);
  fc_k<<<16, 256, 0, stream>>>(pooled, Wf, bfn, outp);
}

// Round 3
// 500.123 us; speedup vs baseline: 2.2419x; 2.2419x over previous
//
#include <hip/hip_runtime.h>

// Problem constants
#define BB 16
#define SS 1024
#define DD 768

typedef _Float16 f16x4 __attribute__((ext_vector_type(4)));
typedef _Float16 f16x8 __attribute__((ext_vector_type(8)));
typedef float f32x4 __attribute__((ext_vector_type(4)));

__device__ __forceinline__ void gload_lds16(const void* g, void* l) {
  __builtin_amdgcn_global_load_lds(
      (const __attribute__((address_space(1))) unsigned int*)g,
      (__attribute__((address_space(3))) unsigned int*)l, 16, 0, 0);
}

// ---------------------------------------------------------------------------
// NT GEMM, fp16 in, single MFMA (m97 structure: global_load_lds staging).
// C[z][m][n] = sum_k A[z][m][k] * Bt[z][n][k] (+ bias[z][n])
// 128x128 tile, BK=32, 256 threads. M,N % 128 == 0, K % 32 == 0.
// OUTM: 0 = fp32 row-major; 1 = fp16 row-major; 2 = fp16 transposed per
//       1024-row batch: C[z][(b*N+c)*1024 + s] with b=row>>10, s=row&1023.
// ---------------------------------------------------------------------------
template<int OUTM, int BIAS>
__global__ __launch_bounds__(256) void gemm_f16(
    const _Float16* __restrict__ A, long long aB,
    const _Float16* __restrict__ Bt, long long bB,
    const float* __restrict__ bias, int biasB,
    void* __restrict__ Cv, long long cB,
    int M, int N, int K)
{
  __shared__ __attribute__((aligned(16))) _Float16 lA[128 * 32];
  __shared__ __attribute__((aligned(16))) _Float16 lB[128 * 32];

  const int t = threadIdx.x;
  const int z = blockIdx.z;
  const _Float16* Ab = A + (size_t)z * aB;
  const _Float16* Bb = Bt + (size_t)z * bB;
  const int m0 = blockIdx.x * 128, n0 = blockIdx.y * 128;
  const int l = t & 63, w = t >> 6;
  const int wr = (w >> 1) * 64, wc = (w & 1) * 64;
  const int lrow = l & 15, lkb = (l >> 4) * 8;

  f32x4 acc[4][4] = {};

  const size_t ldaB = (size_t)K * 2;   // row stride in bytes
  const int o0 = t * 16;               // staging byte offset, issue 0
  const int o1 = o0 + 4096;            // issue 1
  const int rA0 = o0 >> 6, cb0 = o0 & 63;
  const int rA1 = o1 >> 6, cb1 = o1 & 63;

  for (int k0 = 0; k0 < K; k0 += 32) {
    const char* ga = (const char*)Ab + (size_t)k0 * 2;
    const char* gb = (const char*)Bb + (size_t)k0 * 2;
    gload_lds16(ga + (size_t)(m0 + rA0) * ldaB + cb0, (char*)lA + o0);
    gload_lds16(ga + (size_t)(m0 + rA1) * ldaB + cb1, (char*)lA + o1);
    gload_lds16(gb + (size_t)(n0 + rA0) * ldaB + cb0, (char*)lB + o0);
    gload_lds16(gb + (size_t)(n0 + rA1) * ldaB + cb1, (char*)lB + o1);
    __syncthreads();

    f16x8 af[4], bfr[4];
    #pragma unroll
    for (int m = 0; m < 4; m++) af[m]  = *(const f16x8*)&lA[(wr + m * 16 + lrow) * 32 + lkb];
    #pragma unroll
    for (int n = 0; n < 4; n++) bfr[n] = *(const f16x8*)&lB[(wc + n * 16 + lrow) * 32 + lkb];
    #pragma unroll
    for (int m = 0; m < 4; m++)
      #pragma unroll
      for (int n = 0; n < 4; n++)
        acc[m][n] = __builtin_amdgcn_mfma_f32_16x16x32_f16(af[m], bfr[n], acc[m][n], 0, 0, 0);
    __syncthreads();
  }

  // Epilogue: C/D layout col = lane&15, row = 4*(lane>>4) + j
  const int crow = (l >> 4) * 4, ccol = l & 15;
  #pragma unroll
  for (int m = 0; m < 4; m++) {
    const int rq = m0 + wr + m * 16 + crow;
    #pragma unroll
    for (int n = 0; n < 4; n++) {
      const int c = n0 + wc + n * 16 + ccol;
      const float bv = BIAS ? bias[(size_t)z * biasB + c] : 0.0f;
      if (OUTM == 0) {
        float* C = (float*)Cv + (size_t)z * cB;
        #pragma unroll
        for (int j = 0; j < 4; j++)
          C[(size_t)(rq + j) * N + c] = acc[m][n][j] + bv;
      } else if (OUTM == 1) {
        _Float16* C = (_Float16*)Cv + (size_t)z * cB;
        #pragma unroll
        for (int j = 0; j < 4; j++)
          C[(size_t)(rq + j) * N + c] = (_Float16)(acc[m][n][j] + bv);
      } else {
        _Float16* C = (_Float16*)Cv + (size_t)z * cB;
        const int bq = rq >> 10, s = rq & 1023;
        f16x4 o;
        #pragma unroll
        for (int j = 0; j < 4; j++) o[j] = (_Float16)(acc[m][n][j] + bv);
        *(f16x4*)&C[((size_t)(bq * N + c) << 10) + s] = o;
      }
    }
  }
}

// fp32 -> fp16 elementwise cast
__global__ __launch_bounds__(256) void cast_f2h(const float* __restrict__ in,
                                                _Float16* __restrict__ outp, long long n4)
{
  for (long long i = (long long)blockIdx.x * 256 + threadIdx.x; i < n4;
       i += (long long)gridDim.x * 256) {
    float4 v = ((const float4*)in)[i];
    f16x4 r;
    r[0] = (_Float16)v.x; r[1] = (_Float16)v.y; r[2] = (_Float16)v.z; r[3] = (_Float16)v.w;
    ((f16x4*)outp)[i] = r;
  }
}

// fp32 [R][C] -> fp16 [C][R] (weights transpose+cast)
__global__ __launch_bounds__(256) void transpose_f2h(const float* __restrict__ in,
                                                     _Float16* __restrict__ outp, int R, int C)
{
  __shared__ float tile[32][33];
  const int r0 = blockIdx.y * 32, c0 = blockIdx.x * 32;
  const int tx = threadIdx.x & 31, ty = threadIdx.x >> 5;  // 32 x 8
  #pragma unroll
  for (int i = 0; i < 4; i++)
    tile[ty + i * 8][tx] = in[(size_t)(r0 + ty + i * 8) * C + c0 + tx];
  __syncthreads();
  #pragma unroll
  for (int i = 0; i < 4; i++)
    outp[(size_t)(c0 + ty + i * 8) * R + r0 + tx] = (_Float16)tile[tx][ty + i * 8];
}

// fp16 [R][C] -> [C][R], batched over blockIdx.z
__global__ __launch_bounds__(256) void transpose_b2h(const _Float16* __restrict__ in, long long inB,
                                                     _Float16* __restrict__ outp, long long outB,
                                                     int R, int C)
{
  __shared__ _Float16 tile[32][33];
  const _Float16* ib = in + (size_t)blockIdx.z * inB;
  _Float16* ob = outp + (size_t)blockIdx.z * outB;
  const int r0 = blockIdx.y * 32, c0 = blockIdx.x * 32;
  const int tx = threadIdx.x & 31, ty = threadIdx.x >> 5;
  #pragma unroll
  for (int i = 0; i < 4; i++)
    tile[ty + i * 8][tx] = ib[(size_t)(r0 + ty + i * 8) * C + c0 + tx];
  __syncthreads();
  #pragma unroll
  for (int i = 0; i < 4; i++)
    ob[(size_t)(c0 + ty + i * 8) * R + r0 + tx] = tile[tx][ty + i * 8];
}

__global__ void pack2_k(const float* __restrict__ a, const float* __restrict__ b,
                        float* __restrict__ o)
{
  int t = blockIdx.x * 256 + threadIdx.x;
  if (t < 768) o[t] = a[t];
  else if (t < 1536) o[t] = b[t - 768];
}

// Row softmax: fp32 in, fp16 out. L = VPT*256.
template<int VPT>
__global__ __launch_bounds__(256) void softmax_f2h(const float* __restrict__ X,
                                                   _Float16* __restrict__ Y,
                                                   int L, float scale)
{
  const size_t base = (size_t)blockIdx.x * L;
  const int t = threadIdx.x;
  float v[VPT];
  float m = -3.4e38f;
  #pragma unroll
  for (int j = 0; j < VPT; j++) { v[j] = X[base + t + j * 256]; m = fmaxf(m, v[j]); }
  __shared__ float red[256];
  red[t] = m; __syncthreads();
  #pragma unroll
  for (int off = 128; off > 0; off >>= 1) {
    if (t < off) red[t] = fmaxf(red[t], red[t + off]);
    __syncthreads();
  }
  m = red[0]; __syncthreads();
  float s = 0.0f;
  #pragma unroll
  for (int j = 0; j < VPT; j++) { v[j] = __expf((v[j] - m) * scale); s += v[j]; }
  red[t] = s; __syncthreads();
  #pragma unroll
  for (int off = 128; off > 0; off >>= 1) {
    if (t < off) red[t] += red[t + off];
    __syncthreads();
  }
  const float inv = 1.0f / red[0];
  #pragma unroll
  for (int j = 0; j < VPT; j++) Y[base + t + j * 256] = (_Float16)(v[j] * inv);
}

// LayerNorm over (S,D) jointly per batch
__global__ __launch_bounds__(256) void ln_partial(const float* __restrict__ src,
                                                  float* __restrict__ part)
{
  const int b = blockIdx.y, ch = blockIdx.x;   // 64 chunks per batch
  const float4* p = (const float4*)(src + (size_t)b * SS * DD) + (size_t)ch * 3072;
  const int t = threadIdx.x;
  float s = 0.0f, q = 0.0f;
  #pragma unroll
  for (int i = 0; i < 12; i++) {
    float4 v = p[t + i * 256];
    s += v.x + v.y + v.z + v.w;
    q += v.x * v.x + v.y * v.y + v.z * v.z + v.w * v.w;
  }
  __shared__ float rs[256], rq[256];
  rs[t] = s; rq[t] = q; __syncthreads();
  #pragma unroll
  for (int off = 128; off > 0; off >>= 1) {
    if (t < off) { rs[t] += rs[t + off]; rq[t] += rq[t + off]; }
    __syncthreads();
  }
  if (t == 0) { part[(b * 64 + ch) * 2] = rs[0]; part[(b * 64 + ch) * 2 + 1] = rq[0]; }
}

__global__ void ln_final(const float* __restrict__ part, float* __restrict__ stats)
{
  const int b = blockIdx.x, t = threadIdx.x;  // 64 threads = 1 wave
  float s = part[(b * 64 + t) * 2];
  float q = part[(b * 64 + t) * 2 + 1];
  #pragma unroll
  for (int off = 32; off > 0; off >>= 1) { s += __shfl_down(s, off); q += __shfl_down(q, off); }
  if (t == 0) {
    const float invN = 1.0f / (float)(SS * DD);
    float mu = s * invN;
    float var = q * invN - mu * mu;
    stats[b * 2] = mu;
    stats[b * 2 + 1] = rsqrtf(var + 1e-8f);
  }
}

__global__ __launch_bounds__(256) void ln_apply_h(const float* __restrict__ src,
                                                  const float* __restrict__ g,
                                                  const float* __restrict__ bta,
                                                  const float* __restrict__ stats,
                                                  _Float16* __restrict__ dst)
{
  const long long n4 = (long long)BB * SS * DD / 4;
  const int SD4 = SS * DD / 4;
  for (long long i = (long long)blockIdx.x * 256 + threadIdx.x; i < n4;
       i += (long long)gridDim.x * 256) {
    const int b = (int)(i / SD4);
    const int sd4 = (int)(i - (long long)b * SD4);
    const float mu = stats[b * 2], rs = stats[b * 2 + 1];
    float4 v = ((const float4*)src)[i];
    float4 gg = ((const float4*)g)[sd4];
    float4 bb = ((const float4*)bta)[sd4];
    f16x4 r;
    r[0] = (_Float16)((v.x - mu) * rs * gg.x + bb.x);
    r[1] = (_Float16)((v.y - mu) * rs * gg.y + bb.y);
    r[2] = (_Float16)((v.z - mu) * rs * gg.z + bb.z);
    r[3] = (_Float16)((v.w - mu) * rs * gg.w + bb.w);
    ((f16x4*)dst)[i] = r;
  }
}

// gate[b,s] = dot(out_N[b,s,:], W_sgsa) + b_sgsa ; one wave per row
__global__ __launch_bounds__(256) void gate_k(const float* __restrict__ outN,
                                              const float* __restrict__ wsg,
                                              const float* __restrict__ bsg,
                                              float* __restrict__ gate)
{
  const int row = blockIdx.x * 4 + (threadIdx.x >> 6);
  const int l = threadIdx.x & 63;
  const float* src = outN + (size_t)row * DD;
  float s = 0.0f;
  #pragma unroll
  for (int i = 0; i < 12; i++) s += src[l + i * 64] * wsg[l + i * 64];
  #pragma unroll
  for (int off = 32; off > 0; off >>= 1) s += __shfl_down(s, off);
  if (l == 0) gate[row] = s + bsg[0];
}

// Pool stage A: grid (16 chunks, 16 batches); each block: 64 rows x 768 cols
__global__ __launch_bounds__(256) void pool_partial(const float* __restrict__ tokens,
                                                    const float* __restrict__ outN,
                                                    const float* __restrict__ gate,
                                                    float* __restrict__ part)
{
  const int b = blockIdx.y, ch = blockIdx.x, t = threadIdx.x;
  float st0 = 0, st1 = 0, st2 = 0, so0 = 0, so1 = 0, so2 = 0;
  float xt0 = -3.4e38f, xt1 = -3.4e38f, xt2 = -3.4e38f;
  float xo0 = -3.4e38f, xo1 = -3.4e38f, xo2 = -3.4e38f;
  const size_t rowbase = ((size_t)b * SS + ch * 64) * DD;
  for (int i = 0; i < 64; i++) {
    const float* tr = tokens + rowbase + (size_t)i * DD;
    const float* orw = outN + rowbase + (size_t)i * DD;
    const float g = gate[b * SS + ch * 64 + i];
    float t0 = tr[t], t1 = tr[t + 256], t2 = tr[t + 512];
    float o0 = orw[t] * g, o1 = orw[t + 256] * g, o2 = orw[t + 512] * g;
    st0 += t0; st1 += t1; st2 += t2;
    so0 += o0; so1 += o1; so2 += o2;
    xt0 = fmaxf(xt0, t0); xt1 = fmaxf(xt1, t1); xt2 = fmaxf(xt2, t2);
    xo0 = fmaxf(xo0, o0); xo1 = fmaxf(xo1, o1); xo2 = fmaxf(xo2, o2);
  }
  float* pb = part + (size_t)(b * 16 + ch) * 3072;
  pb[t] = st0;          pb[t + 256] = st1;          pb[t + 512] = st2;
  pb[768 + t] = so0;    pb[768 + t + 256] = so1;    pb[768 + t + 512] = so2;
  pb[1536 + t] = xt0;   pb[1536 + t + 256] = xt1;   pb[1536 + t + 512] = xt2;
  pb[2304 + t] = xo0;   pb[2304 + t + 256] = xo1;   pb[2304 + t + 512] = xo2;
}

// Pool stage B: combine 16 chunks -> pooled [B][4*768]
__global__ __launch_bounds__(256) void pool_final(const float* __restrict__ part,
                                                  float* __restrict__ pooled)
{
  const int idx = blockIdx.x * 256 + threadIdx.x;  // < B*D
  const int b = idx / DD, d = idx - b * DD;
  float st = 0, so = 0, xt = -3.4e38f, xo = -3.4e38f;
  for (int ch = 0; ch < 16; ch++) {
    const float* pb = part + (size_t)(b * 16 + ch) * 3072;
    st += pb[d]; so += pb[768 + d];
    xt = fmaxf(xt, pb[1536 + d]); xo = fmaxf(xo, pb[2304 + d]);
  }
  const float inv = 1.0f / (float)SS;
  pooled[(size_t)b * 3072 + d]        = st * inv;
  pooled[(size_t)b * 3072 + 768 + d]  = so * inv;
  pooled[(size_t)b * 3072 + 1536 + d] = xt;
  pooled[(size_t)b * 3072 + 2304 + d] = xo;
}

__global__ __launch_bounds__(256) void fc_k(const float* __restrict__ pooled,
                                            const float* __restrict__ Wf,
                                            const float* __restrict__ bf,
                                            float* __restrict__ outp)
{
  const int b = blockIdx.x, t = threadIdx.x;
  float p0 = 0.0f, p1 = 0.0f;
  #pragma unroll
  for (int i = 0; i < 12; i++) {
    const int j = t + i * 256;
    const float pv = pooled[(size_t)b * 3072 + j];
    p0 += pv * Wf[j * 2];
    p1 += pv * Wf[j * 2 + 1];
  }
  __shared__ float r0[256], r1[256];
  r0[t] = p0; r1[t] = p1; __syncthreads();
  #pragma unroll
  for (int off = 128; off > 0; off >>= 1) {
    if (t < off) { r0[t] += r0[t + off]; r1[t] += r1[t + off]; }
    __syncthreads();
  }
  if (t == 0) {
    outp[b * 2 + 0] = r0[0] + bf[0];
    outp[b * 2 + 1] = r1[0] + bf[1];
  }
}

// ---------------------------------------------------------------------------
// Host orchestration. fp16 GEMM I/O, fp32 softmax/LN/pool chain.
// Region map (byte offsets), peak ~198.6 MB:
//   R0 @ 0         (67.1MB f32): scores -> OUT -> attN_sc -> outN
//   R1 @ 67108864  (25.2MB f16): tokens_h -> out_ln_h -> attNT_h
//   R2 @ 92274688  (25.2MB f16): K_h -> KtN_h
//   R3 @ 117440512 (25.2MB f16): Q_h -> QtN_h
//   R4 @ 142606336 (25.2MB f16): Vt_h -> VN_h
//   R5 @ 167772160 (33.6MB f16): att_h -> attN_h
//   R6 @ 201326592 (3.5MB f16):  Wt_h [3][768*768]
// ---------------------------------------------------------------------------
extern "C" void kernel_launch(void* const* d_in, const int* in_sizes, int n_in,
                              void* d_out, int out_size, void* d_ws, size_t ws_size,
                              hipStream_t stream)
{
  const float* tokens = (const float*)d_in[0];
  const float* Wk  = (const float*)d_in[1];
  const float* bk  = (const float*)d_in[2];
  const float* Wq  = (const float*)d_in[3];
  const float* bq  = (const float*)d_in[4];
  const float* Wv  = (const float*)d_in[5];
  const float* bv  = (const float*)d_in[6];
  const float* lng = (const float*)d_in[7];
  const float* lnb = (const float*)d_in[8];
  const float* Wsg = (const float*)d_in[9];
  const float* bsg = (const float*)d_in[10];
  const float* Wf  = (const float*)d_in[11];
  const float* bfn = (const float*)d_in[12];
  float* outp = (float*)d_out;
  (void)in_sizes; (void)n_in; (void)out_size; (void)ws_size;

  char* ws = (char*)d_ws;
  float*    R0   = (float*)(ws + 0);              // scores/OUT/attN_sc/outN
  _Float16* R1   = (_Float16*)(ws + 67108864);    // tokens_h/out_ln_h/attNT_h
  _Float16* R2   = (_Float16*)(ws + 92274688);    // K_h/KtN_h
  _Float16* R3   = (_Float16*)(ws + 117440512);   // Q_h/QtN_h
  _Float16* R4   = (_Float16*)(ws + 142606336);   // Vt_h/VN_h
  _Float16* R5   = (_Float16*)(ws + 167772160);   // att_h/attN_h
  _Float16* Wt   = (_Float16*)(ws + 201326592);   // 3,538,944 B
  float* pack2   = (float*)(ws + 204865536);      // 6,144 B
  float* part    = (float*)(ws + 204871680);      // 8,192 B
  float* stats   = (float*)(ws + 204879872);      // 128 B
  float* gate    = (float*)(ws + 204880000);      // 65,536 B
  float* ppart   = (float*)(ws + 204945536);      // 3,145,728 B
  float* pooled  = (float*)(ws + 208091264);      // 196,608 B (end ~198.6MB)

  const float fact = 0.036084391824351615f;  // 1/sqrt(768)
  const long long SD = (long long)SS * DD;   // 786432
  const long long S2 = (long long)SS * SS;   // 1048576
  const long long D2 = (long long)DD * DD;   // 589824
  const long long PL = (long long)BB * SD;   // 12582912

  // 1. casts / packing
  cast_f2h<<<2048, 256, 0, stream>>>(tokens, R1, PL / 4);
  transpose_f2h<<<dim3(24, 24), 256, 0, stream>>>(Wk, Wt,               768, 768);
  transpose_f2h<<<dim3(24, 24), 256, 0, stream>>>(Wq, Wt + 589824,      768, 768);
  transpose_f2h<<<dim3(24, 24), 256, 0, stream>>>(Wv, Wt + 2 * 589824,  768, 768);
  pack2_k<<<6, 256, 0, stream>>>(bk, bq, pack2);

  // 2. Stage-1 projections: K_h (R2), Q_h (R3) batched; Vt_h (R4) transposed
  gemm_f16<1, 1><<<dim3(128, 6, 2), 256, 0, stream>>>(R1, 0, Wt, 589824, pack2, 768,
                                                      (void*)R2, PL, BB * SS, DD, DD);
  gemm_f16<2, 1><<<dim3(128, 6, 1), 256, 0, stream>>>(R1, 0, Wt + 2 * 589824, 0, bv, 0,
                                                      (void*)R4, 0, BB * SS, DD, DD);

  // 3. scores = Q.K^T -> R0 fp32 [B,S,S]
  gemm_f16<0, 0><<<dim3(8, 8, 16), 256, 0, stream>>>(R3, SD, R2, SD, nullptr, 0,
                                                     (void*)R0, S2, SS, SS, DD);
  // 4. att_h = softmax(scores*fact) -> R5 fp16
  softmax_f2h<4><<<BB * SS, 256, 0, stream>>>(R0, R5, SS, fact);
  // 5. OUT = att @ V -> R0 fp32 [B,S,D]
  gemm_f16<0, 0><<<dim3(8, 6, 16), 256, 0, stream>>>(R5, S2, R4, SD, nullptr, 0,
                                                     (void*)R0, SD, SS, DD, SS);
  // 6. LayerNorm over (S,D) per batch: stats from fp32, out_ln_h -> R1 fp16
  ln_partial<<<dim3(64, 16), 256, 0, stream>>>(R0, part);
  ln_final<<<16, 64, 0, stream>>>(part, stats);
  ln_apply_h<<<2048, 256, 0, stream>>>(R0, lng, lnb, stats, R1);

  // 7. Stage-2 projections: KtN (R2), QtN (R3) transposed+batched; VN (R4)
  gemm_f16<2, 1><<<dim3(128, 6, 2), 256, 0, stream>>>(R1, 0, Wt, 589824, pack2, 768,
                                                      (void*)R2, PL, BB * SS, DD, DD);
  gemm_f16<1, 1><<<dim3(128, 6, 1), 256, 0, stream>>>(R1, 0, Wt + 2 * 589824, 0, bv, 0,
                                                      (void*)R4, 0, BB * SS, DD, DD);

  // 8. attN_sc[b,d,e] = QtN .NT. KtN -> R0 fp32 [B,D,D]
  gemm_f16<0, 0><<<dim3(6, 6, 16), 256, 0, stream>>>(R3, SD, R2, SD, nullptr, 0,
                                                     (void*)R0, D2, DD, DD, SS);
  // 9. attN_h = softmax -> R5 fp16
  softmax_f2h<3><<<BB * DD, 256, 0, stream>>>(R0, R5, DD, fact);
  // 10. attNT_h -> R1 (out_ln dead)
  transpose_b2h<<<dim3(24, 24, 16), 256, 0, stream>>>(R5, D2, R1, D2, DD, DD);
  // 11. outN = VN .NT. attNT -> R0 fp32 [B,S,D]
  gemm_f16<0, 0><<<dim3(8, 6, 16), 256, 0, stream>>>(R4, SD, R1, D2, nullptr, 0,
                                                     (void*)R0, SD, SS, DD, DD);

  // 12. gate, two-stage pooling, FC
  gate_k<<<4096, 256, 0, stream>>>(R0, Wsg, bsg, gate);
  pool_partial<<<dim3(16, BB), 256, 0, stream>>>(tokens, R0, gate, ppart);
  pool_final<<<48, 256, 0, stream>>>(ppart, pooled);
  fc_k<<<16, 256, 0, stream>>>(pooled, Wf, bfn, outp);
}